// Round 10
// baseline (31.219 us; speedup 1.0000x reference)
//
#include <hip/hip_runtime.h>
#include <hip/hip_bf16.h>

#define D_MODEL 4096
#define NN      4403      // selected neurons
#define NNP     4480      // padded cols = 35*128
#define NB      64        // batch
#define BN      128       // neurons per block (4 waves x 32)
#define KCH     256       // K per block
#define KSPLIT  (D_MODEL / KCH)           // 16
#define NT      ((NN + BN - 1) / BN)      // 35 neuron tiles
#define LDX     264       // shorts per X row in LDS (slot = fr*33 mod 32 distinct -> conflict-free)
#define P_BYTES ((size_t)KSPLIT * NB * NNP * 2)      // ~9.2 MB bf16 partials
#define XBF_BYTES ((size_t)NB * D_MODEL * 2)         // 512 KB
#define WS_NEEDED (P_BYTES + XBF_BYTES)

using f32x4  = __attribute__((ext_vector_type(4))) float;
using bf16x8 = __attribute__((ext_vector_type(8))) short;
using u16x8  = __attribute__((ext_vector_type(8))) unsigned short;
using u16x2  = __attribute__((ext_vector_type(2))) unsigned short;

__device__ __forceinline__ unsigned short f2bf(float f) {
    __hip_bfloat16 h = __float2bfloat16(f);     // RNE
    return __builtin_bit_cast(unsigned short, h);
}

__device__ __forceinline__ u16x8 pack8(f32x4 a, f32x4 b) {
    u16x8 v;
    v[0] = f2bf(a[0]); v[1] = f2bf(a[1]); v[2] = f2bf(a[2]); v[3] = f2bf(a[3]);
    v[4] = f2bf(b[0]); v[5] = f2bf(b[1]); v[6] = f2bf(b[2]); v[7] = f2bf(b[3]);
    return v;
}

// ---------------- Dispatch 1: X fp32 -> bf16 (tiny) ----------------
__global__ __launch_bounds__(256)
void xconv(const float* __restrict__ X, unsigned short* __restrict__ Xbf) {
    const int i = (blockIdx.x * 256 + threadIdx.x) * 8;
    if (i >= NB * D_MODEL) return;
    f32x4 a = *(const f32x4*)(X + i);
    f32x4 b = *(const f32x4*)(X + i + 4);
    *(u16x8*)(Xbf + i) = pack8(a, b);
}

// ---------------- Dispatch 2: gather-GEMM ----------------
// Wave owns 32 neurons x 64 batch. W fully reg-prefetched (16 dwordx4 in
// flight, single latency exposure). X staged as pure bf16 copy (no cvt).
__global__ __launch_bounds__(256, 2)
void gather_gemm(const unsigned short* __restrict__ Xbf,
                 const float* __restrict__ W,
                 const int*   __restrict__ idx,
                 unsigned short* __restrict__ P)
{
    __shared__ __align__(16) unsigned short Xs[64 * LDX];   // 33 KB

    const int tid   = threadIdx.x;
    const int wave  = tid >> 6;
    const int lane  = tid & 63;
    const int fr    = lane & 15;       // neuron within 16-sub-tile
    const int g     = lane >> 4;       // k-group
    const int fk    = g * 8;

    const int n0    = blockIdx.x * BN;
    const int kbase = blockIdx.y * KCH;

    // ---- W: 2 gathered rows per lane, FULL-depth prefetch ----
    const int na = n0 + wave * 32 + fr;
    const int nb = na + 16;
    const int ra = idx[(na < NN) ? na : (NN - 1)];
    const int rb = idx[(nb < NN) ? nb : (NN - 1)];
    const float* wpa = W + (size_t)ra * D_MODEL + kbase + fk;
    const float* wpb = W + (size_t)rb * D_MODEL + kbase + fk;

    f32x4 raw[8][2][2];                // [kfrag][n-half][quad]
#pragma unroll
    for (int kf = 0; kf < 8; ++kf) {
        raw[kf][0][0] = *(const f32x4*)(wpa + kf * 32);
        raw[kf][0][1] = *(const f32x4*)(wpa + kf * 32 + 4);
        raw[kf][1][0] = *(const f32x4*)(wpb + kf * 32);
        raw[kf][1][1] = *(const f32x4*)(wpb + kf * 32 + 4);
    }

    // ---- X staging: pure bf16 copy, 16 B/lane, contiguous 512 B rows ----
    {
        const int row8 = tid >> 5;             // 0..7
        const int cols = (tid & 31) * 8;       // short offset within row
#pragma unroll
        for (int p = 0; p < 8; ++p) {
            const int row = p * 8 + row8;
            u16x8 v = *(const u16x8*)(Xbf + (size_t)row * D_MODEL + kbase + cols);
            *(u16x8*)&Xs[row * LDX + cols] = v;
        }
    }
    __syncthreads();   // single drain: every W + X load retired here

    f32x4 acc[4][2];
#pragma unroll
    for (int m = 0; m < 4; ++m)
#pragma unroll
        for (int j = 0; j < 2; ++j) acc[m][j] = (f32x4){0.f, 0.f, 0.f, 0.f};

    // ---- pure compute: per kfrag, cvt 2 B-frags then 8 MFMA ----
#pragma unroll
    for (int kf = 0; kf < 8; ++kf) {
        bf16x8 b0 = __builtin_bit_cast(bf16x8, pack8(raw[kf][0][0], raw[kf][0][1]));
        bf16x8 b1 = __builtin_bit_cast(bf16x8, pack8(raw[kf][1][0], raw[kf][1][1]));
#pragma unroll
        for (int m = 0; m < 4; ++m) {
            bf16x8 af = *(const bf16x8*)&Xs[(m * 16 + fr) * LDX + kf * 32 + fk];
            acc[m][0] = __builtin_amdgcn_mfma_f32_16x16x32_bf16(af, b0, acc[m][0], 0, 0, 0);
            acc[m][1] = __builtin_amdgcn_mfma_f32_16x16x32_bf16(af, b1, acc[m][1], 0, 0, 0);
        }
    }

    // ---- epilogue: bf16 partials, row-major [slab][row][NNP]; 64 B runs/wave ----
    unsigned short* base = P + (size_t)blockIdx.y * NB * NNP;
#pragma unroll
    for (int j = 0; j < 2; ++j) {
        const int col = n0 + wave * 32 + 16 * j + fr;
#pragma unroll
        for (int m = 0; m < 4; ++m) {
            const int brow = m * 16 + g * 4;
#pragma unroll
            for (int r = 0; r < 4; ++r)
                base[(size_t)(brow + r) * NNP + col] = f2bf(acc[m][j][r]);
        }
    }
}

// ---------------- Dispatch 3: reduce (560 blocks, 2 cols/thread) ----------------
__global__ __launch_bounds__(256)
void reduce_splitk(const unsigned short* __restrict__ P, float* __restrict__ out) {
    const int id = blockIdx.x * 256 + threadIdx.x;
    const int total = NB * NNP / 2;                      // 143360
    if (id >= total) return;
    const int e0  = id * 2;
    const int row = e0 / NNP;
    const int col = e0 % NNP;

    float s0 = 0.f, s1 = 0.f;
#pragma unroll
    for (int sl = 0; sl < KSPLIT; ++sl) {
        u16x2 v = *(const u16x2*)&P[((size_t)sl * NB + row) * NNP + col];
        s0 += __uint_as_float((unsigned)v[0] << 16);
        s1 += __uint_as_float((unsigned)v[1] << 16);
    }
    if (col < NN)     out[(size_t)row * NN + col]     = s0;
    if (col + 1 < NN) out[(size_t)row * NN + col + 1] = s1;
}

// ---------------- Fallback (ws too small): one-pass atomic ----------------
__global__ __launch_bounds__(256, 2)
void gather_gemm_atomic(const float* __restrict__ X,
                        const float* __restrict__ W,
                        const int*   __restrict__ idx,
                        float* __restrict__ out)
{
    __shared__ __align__(16) unsigned short Xs[64 * LDX];
    const int tid  = threadIdx.x;
    const int wave = tid >> 6;
    const int lane = tid & 63;
    const int fr = lane & 15, g = lane >> 4, fk = g * 8;
    const int n0 = blockIdx.x * 64;
    const int kbase = blockIdx.y * KCH;
    const int n = n0 + wave * 16 + fr;
    const int wrow = idx[(n < NN) ? n : (NN - 1)];
    const float* wp = W + (size_t)wrow * D_MODEL + kbase + fk;
    f32x4 wa[8][2];
#pragma unroll
    for (int s = 0; s < 8; ++s) {
        wa[s][0] = *(const f32x4*)(wp + s * 32);
        wa[s][1] = *(const f32x4*)(wp + s * 32 + 4);
    }
    {
        const int row8 = tid >> 5, colf = (tid & 31) * 8;
#pragma unroll
        for (int p = 0; p < 8; ++p) {
            const int row = p * 8 + row8;
            const float* xp = X + (size_t)row * D_MODEL + kbase + colf;
            f32x4 a = *(const f32x4*)(xp + 0);
            f32x4 b = *(const f32x4*)(xp + 4);
            *(u16x8*)&Xs[row * LDX + colf] = pack8(a, b);
        }
    }
    __syncthreads();
    f32x4 acc[4];
#pragma unroll
    for (int m = 0; m < 4; ++m) acc[m] = (f32x4){0.f, 0.f, 0.f, 0.f};
#pragma unroll
    for (int s = 0; s < 8; ++s) {
        bf16x8 wf = __builtin_bit_cast(bf16x8, pack8(wa[s][0], wa[s][1]));
#pragma unroll
        for (int m = 0; m < 4; ++m) {
            bf16x8 af = *(const bf16x8*)&Xs[(m * 16 + fr) * LDX + s * 32 + fk];
            acc[m] = __builtin_amdgcn_mfma_f32_16x16x32_bf16(af, wf, acc[m], 0, 0, 0);
        }
    }
    const int ncol = n0 + wave * 16 + fr;
    if (ncol < NN) {
#pragma unroll
        for (int m = 0; m < 4; ++m) {
            int brow = m * 16 + g * 4;
#pragma unroll
            for (int r = 0; r < 4; ++r)
                atomicAdd(&out[(size_t)(brow + r) * NN + ncol], acc[m][r]);
        }
    }
}

extern "C" void kernel_launch(void* const* d_in, const int* in_sizes, int n_in,
                              void* d_out, int out_size, void* d_ws, size_t ws_size,
                              hipStream_t stream) {
    const float* X   = (const float*)d_in[0];   // [64,1,4096] f32
    const float* W   = (const float*)d_in[1];   // [11008,4096] f32
    const int*   idx = (const int*)d_in[2];     // [4403] i32
    float* out = (float*)d_out;                 // [64,1,4403] f32

    if (ws_size >= WS_NEEDED) {
        unsigned short* P   = (unsigned short*)d_ws;
        unsigned short* Xbf = (unsigned short*)((char*)d_ws + P_BYTES);

        xconv<<<(NB * D_MODEL / 8 + 255) / 256, 256, 0, stream>>>(X, Xbf);

        dim3 grid(NT, KSPLIT, 1);   // 35 x 16 = 560 blocks, 2/CU resident
        gather_gemm<<<grid, 256, 0, stream>>>(Xbf, W, idx, P);

        int total = NB * NNP / 2;   // 143360 threads -> 560 blocks
        reduce_splitk<<<(total + 255) / 256, 256, 0, stream>>>(P, out);
    } else {
        hipMemsetAsync(d_out, 0, (size_t)out_size * sizeof(float), stream);
        dim3 grid((NN + 63) / 64, KSPLIT, 1);
        gather_gemm_atomic<<<grid, 256, 0, stream>>>(X, W, idx, out);
    }
}